// Round 3
// baseline (51.161 us; speedup 1.0000x reference)
//
#include <hip/hip_runtime.h>
#include <hip/hip_bf16.h>

// out[b, 4v+k] = x_in[b,v] + (sum_j x_prev[b,4v+j]) - x_prev[b,4v+k]
// 4 groups per thread: 1x float4 x_in + 4x independent float4 x_prev loads
// issued up-front (max MLP), nontemporal hints (touch-once streams, >> L2).

using f4 = __attribute__((ext_vector_type(4))) float;

__global__ void odd_layer_kernel4(const f4* __restrict__ x_in4,
                                  const f4* __restrict__ pv,
                                  f4* __restrict__ po,
                                  int total_quads) {
    int t = blockIdx.x * blockDim.x + threadIdx.x;
    if (t >= total_quads) return;
    int g = t * 4;
    // Issue all 5 loads before any use.
    f4 p0 = __builtin_nontemporal_load(pv + g);
    f4 p1 = __builtin_nontemporal_load(pv + g + 1);
    f4 p2 = __builtin_nontemporal_load(pv + g + 2);
    f4 p3 = __builtin_nontemporal_load(pv + g + 3);
    f4 xi = __builtin_nontemporal_load(x_in4 + t);

    float s0 = xi[0] + p0[0] + p0[1] + p0[2] + p0[3];
    float s1 = xi[1] + p1[0] + p1[1] + p1[2] + p1[3];
    float s2 = xi[2] + p2[0] + p2[1] + p2[2] + p2[3];
    float s3 = xi[3] + p3[0] + p3[1] + p3[2] + p3[3];

    f4 o0 = {s0 - p0[0], s0 - p0[1], s0 - p0[2], s0 - p0[3]};
    f4 o1 = {s1 - p1[0], s1 - p1[1], s1 - p1[2], s1 - p1[3]};
    f4 o2 = {s2 - p2[0], s2 - p2[1], s2 - p2[2], s2 - p2[3]};
    f4 o3 = {s3 - p3[0], s3 - p3[1], s3 - p3[2], s3 - p3[3]};

    __builtin_nontemporal_store(o0, po + g);
    __builtin_nontemporal_store(o1, po + g + 1);
    __builtin_nontemporal_store(o2, po + g + 2);
    __builtin_nontemporal_store(o3, po + g + 3);
}

extern "C" void kernel_launch(void* const* d_in, const int* in_sizes, int n_in,
                              void* d_out, int out_size, void* d_ws, size_t ws_size,
                              hipStream_t stream) {
    const f4* x_in4 = (const f4*)d_in[0];   // [B, V] = [2048, 2048]
    const f4* pv    = (const f4*)d_in[1];   // [B, E] = [2048, 8192], E groups of 4
    f4* po          = (f4*)d_out;

    const int total_quads = out_size / 16;  // B*V/4 = 1,048,576 threads
    const int block = 256;
    int grid = (total_quads + block - 1) / block;   // 4096 blocks, exact fit
    odd_layer_kernel4<<<grid, block, 0, stream>>>(x_in4, pv, po, total_quads);
}

// Round 4
// 27.076 us; speedup vs baseline: 1.8895x; 1.8895x over previous
//
#include <hip/hip_runtime.h>
#include <hip/hip_bf16.h>

// out[b, 4v+k] = x_in[b,v] + (sum_j x_prev[b,4v+j]) - x_prev[b,4v+k]
// 4 groups per thread at BLOCK-STRIDED offsets: every load instruction is
// lane-contiguous (full coalescing), 4 independent load chains (MLP).
// No nontemporal hints (R3 post-mortem: nt + reuse-bearing lines = refetch).

using f4 = __attribute__((ext_vector_type(4))) float;

__global__ void odd_layer_kernel5(const float* __restrict__ x_in,
                                  const f4* __restrict__ pv,
                                  f4* __restrict__ po) {
    // Each block covers 1024 contiguous groups: 4 chunks of 256.
    int base = blockIdx.x * 1024 + threadIdx.x;
    int g0 = base;
    int g1 = base + 256;
    int g2 = base + 512;
    int g3 = base + 768;

    // Issue all loads before any use.
    f4 p0 = pv[g0];
    f4 p1 = pv[g1];
    f4 p2 = pv[g2];
    f4 p3 = pv[g3];
    float x0 = x_in[g0];
    float x1 = x_in[g1];
    float x2 = x_in[g2];
    float x3 = x_in[g3];

    float s0 = x0 + p0[0] + p0[1] + p0[2] + p0[3];
    float s1 = x1 + p1[0] + p1[1] + p1[2] + p1[3];
    float s2 = x2 + p2[0] + p2[1] + p2[2] + p2[3];
    float s3 = x3 + p3[0] + p3[1] + p3[2] + p3[3];

    f4 o0 = {s0 - p0[0], s0 - p0[1], s0 - p0[2], s0 - p0[3]};
    f4 o1 = {s1 - p1[0], s1 - p1[1], s1 - p1[2], s1 - p1[3]};
    f4 o2 = {s2 - p2[0], s2 - p2[1], s2 - p2[2], s2 - p2[3]};
    f4 o3 = {s3 - p3[0], s3 - p3[1], s3 - p3[2], s3 - p3[3]};

    po[g0] = o0;
    po[g1] = o1;
    po[g2] = o2;
    po[g3] = o3;
}

extern "C" void kernel_launch(void* const* d_in, const int* in_sizes, int n_in,
                              void* d_out, int out_size, void* d_ws, size_t ws_size,
                              hipStream_t stream) {
    const float* x_in = (const float*)d_in[0];  // [B, V] = [2048, 2048]
    const f4* pv      = (const f4*)d_in[1];     // [B, E] as B*V groups of 4
    f4* po            = (f4*)d_out;

    const int total_groups = out_size / 4;      // 4,194,304; divisible by 1024
    const int block = 256;
    int grid = total_groups / 1024;             // 4096 blocks, exact fit
    odd_layer_kernel5<<<grid, block, 0, stream>>>(x_in, pv, po);
}